// Round 1
// baseline (968.723 us; speedup 1.0000x reference)
//
#include <hip/hip_runtime.h>

// KoopmanOperator: y_{t+1} = rot(exp/cos/sin of p) * y_t, p = tanh(y W1^T + b1) W2^T + b2
// Layout: one wave (64 lanes) per batch row. Lane j holds W1 row j and W2 row j
// in VGPRs (64+64 regs). y/h live in per-block LDS, read as broadcast float4.
// Output store: 64 consecutive floats per wave per step (coalesced, 256B).

#define T_STEPS 256
#define DD 64
#define DT 0.01f

__global__ __launch_bounds__(64) void koopman_kernel(
    const float* __restrict__ x,
    const float* __restrict__ W1, const float* __restrict__ b1,
    const float* __restrict__ W2, const float* __restrict__ b2,
    float* __restrict__ out)
{
    const int row = blockIdx.x;        // 0..4095
    const int j   = threadIdx.x;       // 0..63

    __shared__ float sh_y[DD];
    __shared__ float sh_h[DD];

    // Preload weight rows into registers: lane j gets W1[j,:], W2[j,:]
    float w1r[DD], w2r[DD];
    #pragma unroll
    for (int k4 = 0; k4 < DD / 4; ++k4) {
        float4 a = *(const float4*)(W1 + (size_t)j * DD + 4 * k4);
        w1r[4*k4+0] = a.x; w1r[4*k4+1] = a.y; w1r[4*k4+2] = a.z; w1r[4*k4+3] = a.w;
        float4 b = *(const float4*)(W2 + (size_t)j * DD + 4 * k4);
        w2r[4*k4+0] = b.x; w2r[4*k4+1] = b.y; w2r[4*k4+2] = b.z; w2r[4*k4+3] = b.w;
    }
    const float b1r = b1[j];
    const float b2r = b2[j];

    // y0 = x[row, 0, j]
    float yreg = x[(size_t)row * T_STEPS * DD + j];
    sh_y[j] = yreg;
    __syncthreads();

    float* outrow = out + (size_t)row * T_STEPS * DD;
    const bool even = ((j & 1) == 0);

    for (int t = 0; t < T_STEPS; ++t) {
        // ---- h = tanh(W1 y + b1): lane j computes h_j ----
        float a0 = 0.f, a1 = 0.f, a2 = 0.f, a3 = 0.f;
        #pragma unroll
        for (int k4 = 0; k4 < DD / 4; ++k4) {
            float4 yv = *(const float4*)(sh_y + 4 * k4);   // broadcast read
            a0 += w1r[4*k4+0] * yv.x;
            a1 += w1r[4*k4+1] * yv.y;
            a2 += w1r[4*k4+2] * yv.z;
            a3 += w1r[4*k4+3] * yv.w;
        }
        float hx = (a0 + a1) + (a2 + a3) + b1r;
        // tanh(x) = 1 - 2/(exp(2x)+1); saturates correctly for |x| large
        float ex = __expf(2.0f * hx);
        float th = 1.0f - __fdividef(2.0f, ex + 1.0f);
        sh_h[j] = th;
        __syncthreads();

        // ---- p = W2 h + b2: lane j computes p_j ----
        a0 = 0.f; a1 = 0.f; a2 = 0.f; a3 = 0.f;
        #pragma unroll
        for (int k4 = 0; k4 < DD / 4; ++k4) {
            float4 hv = *(const float4*)(sh_h + 4 * k4);   // broadcast read
            a0 += w2r[4*k4+0] * hv.x;
            a1 += w2r[4*k4+1] * hv.y;
            a2 += w2r[4*k4+2] * hv.z;
            a3 += w2r[4*k4+3] * hv.w;
        }
        float p = (a0 + a1) + (a2 + a3) + b2r;

        // ---- rotation update: pairs (2i, 2i+1) ----
        float p_o = __shfl_xor(p, 1, 64);
        float y_o = __shfl_xor(yreg, 1, 64);
        float mu = even ? p   : p_o;   // p[2i]
        float om = even ? p_o : p;     // p[2i+1]
        float y0 = even ? yreg : y_o;  // y[2i]
        float y1 = even ? y_o  : yreg; // y[2i+1]

        float e = __expf(DT * mu);
        float c = __cosf(DT * om);
        float s = __sinf(DT * om);
        // n0 = e*(c*y0 - s*y1);  n1 = e*(s*y0 - c*y1)   (reference signs verbatim)
        float n = even ? e * (c * y0 - s * y1)
                       : e * (s * y0 - c * y1);
        yreg = n;

        __syncthreads();   // all reads of sh_y/sh_h for this step done
        sh_y[j] = n;
        outrow[t * DD + j] = n;
        __syncthreads();   // sh_y ready for next step
    }
}

extern "C" void kernel_launch(void* const* d_in, const int* in_sizes, int n_in,
                              void* d_out, int out_size, void* d_ws, size_t ws_size,
                              hipStream_t stream) {
    const float* x  = (const float*)d_in[0];
    const float* W1 = (const float*)d_in[1];
    const float* b1 = (const float*)d_in[2];
    const float* W2 = (const float*)d_in[3];
    const float* b2 = (const float*)d_in[4];
    float* out = (float*)d_out;

    dim3 grid(4096);
    dim3 block(64);
    koopman_kernel<<<grid, block, 0, stream>>>(x, W1, b1, W2, b2, out);
}